// Round 1
// baseline (207.593 us; speedup 1.0000x reference)
//
#include <hip/hip_runtime.h>
#include <stdint.h>

#define IN_F 512
#define OUT_F 512
#define NROWS 8192
#define NSLOT 12                 // 11 spline slots + 1 base(x) slot per in-feature
#define KTOT (IN_F * NSLOT)      // 6144
#define K16S (KTOT / 16)         // 384 k16-steps
#define BK 96                    // 8 in-features per K iteration
#define NITER (KTOT / BK)        // 64
#define APAD_ROW 120             // 96 slots + 24 pad: 60-word row stride -> conflict-free b128

typedef __bf16 bf16x8 __attribute__((ext_vector_type(8)));
typedef float f32x16 __attribute__((ext_vector_type(16)));

// Static device buffer for transformed weights (frag-linear B-operand layout):
// chunk index (k16, ntile, lane) -> 8 bf16 = B[k16*16 + (lane>>5)*8 + j][ntile*32 + (lane&31)]
__device__ ushort g_Wb[K16S * 16 * 64 * 8];   // 6.29 MB

__device__ __forceinline__ ushort f2bf(float f) {
    uint32_t u = __builtin_bit_cast(uint32_t, f);
    u += 0x7FFFu + ((u >> 16) & 1u);          // RNE
    return (ushort)(u >> 16);
}

// ---------------- weight prep: (o,i,j) fp32 -> frag-linear bf16 -------------
__global__ __launch_bounds__(256) void prep_weights(const float* __restrict__ bw,
                                                    const float* __restrict__ sw) {
    __shared__ __align__(16) ushort buf[24 * 64 * 8];   // 24 k16-chunks of this block
    const int t  = threadIdx.x;
    const int nt = blockIdx.x & 15;   // ntile: outs [nt*32, nt*32+32)
    const int fg = blockIdx.x >> 4;   // fgroup: feats [fg*32, fg*32+32) -> k16 [fg*24, fg*24+24)

    #pragma unroll
    for (int p = 0; p < 4; ++p) {
        int idx = t + p * 256;        // 0..1023 = 32 outs x 32 feats
        int o_l = idx >> 5;
        int f_l = idx & 31;           // lanes sweep f -> near-contiguous sw reads
        int o = nt * 32 + o_l;
        int f = fg * 32 + f_l;
        const float* swp = sw + ((size_t)o * IN_F + f) * 11;
        float v[12];
        #pragma unroll
        for (int j = 0; j < 11; ++j) v[j] = swp[j];
        v[11] = bw[o * IN_F + f];     // base weight lives in slot 11
        #pragma unroll
        for (int j = 0; j < 12; ++j) {
            int k_l  = f_l * NSLOT + j;          // 0..383
            int k16l = k_l >> 4;
            int kk   = k_l & 15;
            int lane = o_l + ((kk >> 3) << 5);
            int slot = kk & 7;
            buf[(k16l * 64 + lane) * 8 + slot] = f2bf(v[j]);
        }
    }
    __syncthreads();
    const uint4* src = (const uint4*)buf;
    #pragma unroll
    for (int r = 0; r < 6; ++r) {
        int c = t + r * 256;          // 0..1535 chunks
        int k16l = c >> 6;
        int lane = c & 63;
        ((uint4*)g_Wb)[((size_t)(fg * 24 + k16l) * 16 + nt) * 64 + lane] = src[c];
    }
}

// ---------------- fused basis + GEMM ----------------------------------------
__global__ __launch_bounds__(256, 1) void kan_gemm(const float* __restrict__ x,
                                                   float* __restrict__ out) {
    __shared__ __align__(16) ushort As[128 * APAD_ROW];   // 30720 B

    const int t    = threadIdx.x;
    const int lane = t & 63;
    const int w    = t >> 6;
    const int ln31 = lane & 31;
    const int half = lane >> 5;

    const int bx = blockIdx.x;
    const int ng = bx & 3;            // N-group: aligns with XCD round-robin (bx%8)
    const int mb = bx >> 2;
    const int row_base = mb * 128;
    const int col_base = ng * 128;
    const int wm = (w & 1) * 64;
    const int wn = (w >> 1) * 64;

    // staging ownership: thread -> (row, 4 features)
    const int sm = t >> 1;            // 0..127
    const int fh = t & 1;             // which half (4 feats) of the 8-feature chunk

    f32x16 acc[2][2] = {};

    #pragma unroll 1
    for (int it = 0; it < NITER; ++it) {
        // -- prefetch this iteration's B fragments (global, frag-linear, coalesced)
        uint4 breg[6][2];
        #pragma unroll
        for (int ks = 0; ks < 6; ++ks) {
            int k16g = it * 6 + ks;
            #pragma unroll
            for (int nt = 0; nt < 2; ++nt) {
                int ntg = ng * 4 + (w >> 1) * 2 + nt;
                breg[ks][nt] = ((const uint4*)g_Wb)[((size_t)k16g * 16 + ntg) * 64 + lane];
            }
        }

        __syncthreads();   // previous iteration's frag reads done before restaging

        // -- stage A tile: basis eval, select-pack, 3x ds_write_b64 per feature
        {
            const float4 xv = *(const float4*)&x[(size_t)(row_base + sm) * IN_F + it * 8 + fh * 4];
            #pragma unroll
            for (int c = 0; c < 4; ++c) {
                float xx = (c == 0) ? xv.x : (c == 1) ? xv.y : (c == 2) ? xv.z : xv.w;
                float wpos = (xx + 1.0f) * 7.0f;
                float fi = floorf(wpos);
                int   i  = (int)fi;
                float u  = wpos - fi;
                bool inr = (xx >= -1.0f) && (xx < 1.0f);
                int   q  = i - 3;                       // first (possibly invalid) slot
                float um = 1.0f - u;
                float uu = u * u, u3 = uu * u;
                const float C6 = 1.0f / 6.0f;
                float s0 = (inr && q >= 0) ? C6 : 0.0f;             // slot q     valid
                float s1 = (inr && q >= -1 && q <= 9) ? C6 : 0.0f;  // slot q+1
                float s2 = (inr && q >= -2 && q <= 8) ? C6 : 0.0f;  // slot q+2
                float s3 = (inr && q <= 7) ? C6 : 0.0f;             // slot q+3
                uint b0 = f2bf(um * um * um * s0);
                uint b1 = f2bf((3.0f * u3 - 6.0f * uu + 4.0f) * s1);
                uint b2 = f2bf((-3.0f * u3 + 3.0f * uu + 3.0f * u + 1.0f) * s2);
                uint b3 = f2bf(u3 * s3);
                int r  = q & 1;
                int e0 = q & ~1;                        // even-aligned window start
                uint P0 = r ? (b0 << 16)        : (b0 | (b1 << 16));
                uint P1 = r ? (b1 | (b2 << 16)) : (b2 | (b3 << 16));
                uint P2 = r ? b3                : 0u;
                uint p[6];
                #pragma unroll
                for (int pi = 0; pi < 6; ++pi) {
                    int d = 2 * pi - e0;
                    p[pi] = (d == 0) ? P0 : (d == 2) ? P1 : (d == 4) ? P2 : 0u;
                }
                p[5] = (p[5] & 0xFFFFu) | ((uint)f2bf(xx) << 16);   // slot 11 = raw x
                ushort* rowp = &As[sm * APAD_ROW + (fh * 4 + c) * NSLOT];
                uint2 w0; w0.x = p[0]; w0.y = p[1];
                uint2 w1; w1.x = p[2]; w1.y = p[3];
                uint2 w2; w2.x = p[4]; w2.y = p[5];
                *(uint2*)&rowp[0] = w0;
                *(uint2*)&rowp[4] = w1;
                *(uint2*)&rowp[8] = w2;
            }
        }

        __syncthreads();

        // -- MFMA over 6 k16-steps
        #pragma unroll
        for (int ks = 0; ks < 6; ++ks) {
            uint4 a0 = *(const uint4*)&As[(wm + ln31) * APAD_ROW + ks * 16 + half * 8];
            uint4 a1 = *(const uint4*)&As[(wm + 32 + ln31) * APAD_ROW + ks * 16 + half * 8];
            bf16x8 af0 = __builtin_bit_cast(bf16x8, a0);
            bf16x8 af1 = __builtin_bit_cast(bf16x8, a1);
            bf16x8 bf0 = __builtin_bit_cast(bf16x8, breg[ks][0]);
            bf16x8 bf1 = __builtin_bit_cast(bf16x8, breg[ks][1]);
            acc[0][0] = __builtin_amdgcn_mfma_f32_32x32x16_bf16(af0, bf0, acc[0][0], 0, 0, 0);
            acc[0][1] = __builtin_amdgcn_mfma_f32_32x32x16_bf16(af0, bf1, acc[0][1], 0, 0, 0);
            acc[1][0] = __builtin_amdgcn_mfma_f32_32x32x16_bf16(af1, bf0, acc[1][0], 0, 0, 0);
            acc[1][1] = __builtin_amdgcn_mfma_f32_32x32x16_bf16(af1, bf1, acc[1][1], 0, 0, 0);
        }
    }

    // -- epilogue: C layout col=lane&31, row=(reg&3)+8*(reg>>2)+4*(lane>>5)
    #pragma unroll
    for (int mt = 0; mt < 2; ++mt) {
        #pragma unroll
        for (int nt = 0; nt < 2; ++nt) {
            int rb = row_base + wm + mt * 32 + 4 * half;
            int cc = col_base + wn + nt * 32 + ln31;
            #pragma unroll
            for (int reg = 0; reg < 16; ++reg) {
                int rr = rb + (reg & 3) + 8 * (reg >> 2);
                out[(size_t)rr * OUT_F + cc] = acc[mt][nt][reg];
            }
        }
    }
}

extern "C" void kernel_launch(void* const* d_in, const int* in_sizes, int n_in,
                              void* d_out, int out_size, void* d_ws, size_t ws_size,
                              hipStream_t stream) {
    const float* x  = (const float*)d_in[0];
    const float* bw = (const float*)d_in[1];
    const float* sw = (const float*)d_in[2];
    float* out = (float*)d_out;
    hipLaunchKernelGGL(prep_weights, dim3(256), dim3(256), 0, stream, bw, sw);
    hipLaunchKernelGGL(kan_gemm, dim3(256), dim3(256), 0, stream, x, out);
}

// Round 2
// 184.005 us; speedup vs baseline: 1.1282x; 1.1282x over previous
//
#include <hip/hip_runtime.h>
#include <stdint.h>

#define IN_F 512
#define OUT_F 512
#define NROWS 8192
#define NSLOT 12                 // 11 spline slots + 1 base(x) slot per in-feature
#define KTOT (IN_F * NSLOT)      // 6144
#define K16S (KTOT / 16)         // 384 k16-steps
#define BK 96                    // 8 in-features per K iteration
#define NITER (KTOT / BK)        // 64 total; 16 per K-split piece
#define KSPLIT 4
#define APAD_ROW 120             // 96 slots + 24 pad: 60-word row stride -> conflict-free b128
#define SW_ROW (IN_F * 11)       // 5632 floats per output row of spline_weight

typedef __bf16 bf16x8 __attribute__((ext_vector_type(8)));
typedef float f32x16 __attribute__((ext_vector_type(16)));

// Static device buffer for transformed weights (frag-linear B-operand layout):
// uint4 index (k16*16 + ntile)*64 + lane  ->  8 bf16 =
//   B[k16*16 + (lane>>5)*8 + j][ntile*32 + (lane&31)],  k = f*12 + j_slot
__device__ ushort g_Wb[K16S * 16 * 64 * 8];   // 6.29 MB

__device__ __forceinline__ ushort f2bf(float f) {
    uint32_t u = __builtin_bit_cast(uint32_t, f);
    u += 0x7FFFu + ((u >> 16) & 1u);          // RNE
    return (ushort)(u >> 16);
}

// ---------------- weight prep: one block per output row o -------------------
// Coalesced float4 reads of the contiguous sw row; bf16 k-column in LDS;
// frag-linear 16B stores (uncoalesced but only 6.3 MB, absorbed by L2).
__global__ __launch_bounds__(64) void prep_weights(const float* __restrict__ bw,
                                                   const float* __restrict__ sw) {
    __shared__ __align__(16) ushort kcol[KTOT];   // 12 KB
    const int o    = blockIdx.x;
    const int lane = threadIdx.x;
    const float* swr = sw + (size_t)o * SW_ROW;

    #pragma unroll
    for (int i = 0; i < 22; ++i) {
        int idx4 = lane + i * 64;                 // 0..1407
        float4 v = ((const float4*)swr)[idx4];
        uint p = (uint)idx4 * 4;
        #pragma unroll
        for (int c = 0; c < 4; ++c) {
            uint pc = p + c;
            uint f = pc / 11u;                    // magic-mul
            uint j = pc - f * 11u;
            float val = (c == 0) ? v.x : (c == 1) ? v.y : (c == 2) ? v.z : v.w;
            kcol[f * NSLOT + j] = f2bf(val);
        }
    }
    #pragma unroll
    for (int i = 0; i < 8; ++i) {
        int f = lane + i * 64;
        kcol[f * NSLOT + 11] = f2bf(bw[(size_t)o * IN_F + f]);
    }
    __syncthreads();

    const int nt = o >> 5;
    const int ol = o & 31;
    #pragma unroll
    for (int c = 0; c < 12; ++c) {
        int chunk = lane + c * 64;                // 0..767
        int k16   = chunk >> 1;
        int half  = chunk & 1;
        uint4 val = *(const uint4*)&kcol[k16 * 16 + half * 8];
        ((uint4*)g_Wb)[((size_t)(k16 * 16 + nt)) * 64 + ol + 32 * half] = val;
    }
}

// ---------------- fused basis + GEMM (K-split x4, atomic epilogue) ----------
__global__ __launch_bounds__(256, 3) void kan_gemm(const float* __restrict__ x,
                                                   float* __restrict__ out) {
    __shared__ __align__(16) ushort As[128 * APAD_ROW];   // 30720 B

    const int t    = threadIdx.x;
    const int lane = t & 63;
    const int w    = t >> 6;
    const int ln31 = lane & 31;
    const int half = lane >> 5;

    const int bx = blockIdx.x;
    const int ng = bx & 3;            // N-group (bx%8 spreads (ng,kp) across XCDs)
    const int kp = (bx >> 2) & 3;     // K-split piece
    const int mb = bx >> 4;           // M-tile 0..63
    const int row_base = mb * 128;
    const int col_base = ng * 128;
    const int wm = (w & 1) * 64;
    const int wn = (w >> 1) * 64;

    // staging ownership: thread -> (row, 4 features)
    const int sm = t >> 1;            // 0..127
    const int fh = t & 1;             // which half (4 feats) of the 8-feature chunk

    f32x16 acc[2][2] = {};

    const int it0 = kp * (NITER / KSPLIT);
    #pragma unroll 1
    for (int ii = 0; ii < NITER / KSPLIT; ++ii) {
        const int it = it0 + ii;
        // -- prefetch this iteration's B fragments (global, frag-linear, coalesced)
        uint4 breg[6][2];
        #pragma unroll
        for (int ks = 0; ks < 6; ++ks) {
            int k16g = it * 6 + ks;
            #pragma unroll
            for (int nt = 0; nt < 2; ++nt) {
                int ntg = ng * 4 + (w >> 1) * 2 + nt;
                breg[ks][nt] = ((const uint4*)g_Wb)[((size_t)k16g * 16 + ntg) * 64 + lane];
            }
        }
        // -- prefetch this thread's x quad (consumed after the barrier)
        const float4 xv = *(const float4*)&x[(size_t)(row_base + sm) * IN_F + it * 8 + fh * 4];

        __syncthreads();   // previous iteration's frag reads done before restaging

        // -- stage A tile: basis eval, select-pack, 3x ds_write_b64 per feature
        {
            #pragma unroll
            for (int c = 0; c < 4; ++c) {
                float xx = (c == 0) ? xv.x : (c == 1) ? xv.y : (c == 2) ? xv.z : xv.w;
                float wpos = (xx + 1.0f) * 7.0f;
                float fi = floorf(wpos);
                int   i  = (int)fi;
                float u  = wpos - fi;
                bool inr = (xx >= -1.0f) && (xx < 1.0f);
                int   q  = i - 3;                       // first (possibly invalid) slot
                float um = 1.0f - u;
                float uu = u * u, u3 = uu * u;
                const float C6 = 1.0f / 6.0f;
                float s0 = (inr && q >= 0) ? C6 : 0.0f;             // slot q     valid
                float s1 = (inr && q >= -1 && q <= 9) ? C6 : 0.0f;  // slot q+1
                float s2 = (inr && q >= -2 && q <= 8) ? C6 : 0.0f;  // slot q+2
                float s3 = (inr && q <= 7) ? C6 : 0.0f;             // slot q+3
                uint b0 = f2bf(um * um * um * s0);
                uint b1 = f2bf((3.0f * u3 - 6.0f * uu + 4.0f) * s1);
                uint b2 = f2bf((-3.0f * u3 + 3.0f * uu + 3.0f * u + 1.0f) * s2);
                uint b3 = f2bf(u3 * s3);
                int r  = q & 1;
                int e0 = q & ~1;                        // even-aligned window start
                uint P0 = r ? (b0 << 16)        : (b0 | (b1 << 16));
                uint P1 = r ? (b1 | (b2 << 16)) : (b2 | (b3 << 16));
                uint P2 = r ? b3                : 0u;
                uint p[6];
                #pragma unroll
                for (int pi = 0; pi < 6; ++pi) {
                    int d = 2 * pi - e0;
                    p[pi] = (d == 0) ? P0 : (d == 2) ? P1 : (d == 4) ? P2 : 0u;
                }
                p[5] = (p[5] & 0xFFFFu) | ((uint)f2bf(xx) << 16);   // slot 11 = raw x
                ushort* rowp = &As[sm * APAD_ROW + (fh * 4 + c) * NSLOT];
                uint2 w0; w0.x = p[0]; w0.y = p[1];
                uint2 w1; w1.x = p[2]; w1.y = p[3];
                uint2 w2; w2.x = p[4]; w2.y = p[5];
                *(uint2*)&rowp[0] = w0;
                *(uint2*)&rowp[4] = w1;
                *(uint2*)&rowp[8] = w2;
            }
        }

        __syncthreads();

        // -- MFMA over 6 k16-steps
        #pragma unroll
        for (int ks = 0; ks < 6; ++ks) {
            uint4 a0 = *(const uint4*)&As[(wm + ln31) * APAD_ROW + ks * 16 + half * 8];
            uint4 a1 = *(const uint4*)&As[(wm + 32 + ln31) * APAD_ROW + ks * 16 + half * 8];
            bf16x8 af0 = __builtin_bit_cast(bf16x8, a0);
            bf16x8 af1 = __builtin_bit_cast(bf16x8, a1);
            bf16x8 bf0 = __builtin_bit_cast(bf16x8, breg[ks][0]);
            bf16x8 bf1 = __builtin_bit_cast(bf16x8, breg[ks][1]);
            acc[0][0] = __builtin_amdgcn_mfma_f32_32x32x16_bf16(af0, bf0, acc[0][0], 0, 0, 0);
            acc[0][1] = __builtin_amdgcn_mfma_f32_32x32x16_bf16(af0, bf1, acc[0][1], 0, 0, 0);
            acc[1][0] = __builtin_amdgcn_mfma_f32_32x32x16_bf16(af1, bf0, acc[1][0], 0, 0, 0);
            acc[1][1] = __builtin_amdgcn_mfma_f32_32x32x16_bf16(af1, bf1, acc[1][1], 0, 0, 0);
        }
    }

    // -- epilogue: C layout col=lane&31, row=(reg&3)+8*(reg>>2)+4*(lane>>5)
    #pragma unroll
    for (int mt = 0; mt < 2; ++mt) {
        #pragma unroll
        for (int nt = 0; nt < 2; ++nt) {
            int rb = row_base + wm + mt * 32 + 4 * half;
            int cc = col_base + wn + nt * 32 + ln31;
            #pragma unroll
            for (int reg = 0; reg < 16; ++reg) {
                int rr = rb + (reg & 3) + 8 * (reg >> 2);
                unsafeAtomicAdd(&out[(size_t)rr * OUT_F + cc], acc[mt][nt][reg]);
            }
        }
    }
}

extern "C" void kernel_launch(void* const* d_in, const int* in_sizes, int n_in,
                              void* d_out, int out_size, void* d_ws, size_t ws_size,
                              hipStream_t stream) {
    const float* x  = (const float*)d_in[0];
    const float* bw = (const float*)d_in[1];
    const float* sw = (const float*)d_in[2];
    float* out = (float*)d_out;
    hipMemsetAsync(out, 0, (size_t)out_size * sizeof(float), stream);
    hipLaunchKernelGGL(prep_weights, dim3(512), dim3(64), 0, stream, bw, sw);
    hipLaunchKernelGGL(kan_gemm, dim3(64 * 4 * KSPLIT), dim3(256), 0, stream, x, out);
}

// Round 3
// 174.190 us; speedup vs baseline: 1.1918x; 1.0563x over previous
//
#include <hip/hip_runtime.h>
#include <stdint.h>

#define IN_F 512
#define OUT_F 512
#define NROWS 8192
#define NSLOT 12                 // 11 spline slots + 1 base(x) slot per in-feature
#define KTOT (IN_F * NSLOT)      // 6144
#define K16S (KTOT / 16)         // 384 k16-steps
#define KSPLIT 4                 // grid = 64 mtiles x 4 kpieces; same-XCD per mtile
#define ITERS 16                 // K-iters per block (8 feats = 96 k-slots each)
#define APAD_ROW 120             // 96 slots + 24 pad (16B-aligned rows; 4-way measured-mild)
#define SW_ROW (IN_F * 11)       // 5632 floats per output row of spline_weight
#define KC_PAD 776               // kcol row stride (ushorts): 1552B, 16B-aligned

typedef __bf16 bf16x8 __attribute__((ext_vector_type(8)));
typedef float f32x16 __attribute__((ext_vector_type(16)));

// frag-linear B: uint4 index (k16*16 + ntile)*64 + lane -> 8 bf16 =
//   B[k16*16 + (lane>>5)*8 + j][ntile*32 + (lane&31)],  k = f*12 + j_slot
__device__ ushort g_Wb[K16S * 16 * 64 * 8];   // 6.29 MB

__device__ __forceinline__ ushort f2bf(float f) {
    uint32_t u = __builtin_bit_cast(uint32_t, f);
    u += 0x7FFFu + ((u >> 16) & 1u);          // RNE
    return (ushort)(u >> 16);
}

// ---- weight prep: 16 ntile x 8 kgroup blocks; coalesced in AND out ---------
__global__ __launch_bounds__(256) void prep_weights(const float* __restrict__ bw,
                                                    const float* __restrict__ sw) {
    __shared__ __align__(16) ushort kcol[32 * KC_PAD];    // 48.5 KB
    const int t  = threadIdx.x;
    const int nt = blockIdx.x & 15;           // outs [nt*32, +32)
    const int kg = blockIdx.x >> 4;           // feats [kg*64, +64) -> k16 [kg*48, +48)
    const int o0 = nt * 32;
    const int f0 = kg * 64;

    // phase 1: sw row-slices (704 floats each) -> bf16 k-columns in LDS
    {
        const int o_l = t >> 3;               // 0..31
        const int tr  = t & 7;                // 8 threads per row
        const float* swr = sw + (size_t)(o0 + o_l) * SW_ROW + (size_t)f0 * 11;
        #pragma unroll
        for (int i = 0; i < 22; ++i) {
            int p4 = tr + i * 8;              // float4 idx 0..175
            float4 v = ((const float4*)swr)[p4];
            uint pos = (uint)p4 * 4;
            #pragma unroll
            for (int c = 0; c < 4; ++c) {
                uint pc = pos + c;            // 0..703
                uint fl = pc / 11u;
                uint j  = pc - fl * 11u;
                float val = (c == 0) ? v.x : (c == 1) ? v.y : (c == 2) ? v.z : v.w;
                kcol[o_l * KC_PAD + fl * NSLOT + j] = f2bf(val);
            }
        }
        #pragma unroll
        for (int i = 0; i < 8; ++i) {
            int fl = tr + i * 8;              // 0..63
            kcol[o_l * KC_PAD + fl * NSLOT + 11] =
                f2bf(bw[(size_t)(o0 + o_l) * IN_F + f0 + fl]);
        }
    }
    __syncthreads();

    // phase 2: frag-linear 16B stores, 32-lane coalesced (512B bursts)
    {
        const int ol = t & 31;
        const int ph = t >> 5;                // 0..7
        #pragma unroll
        for (int i = 0; i < 12; ++i) {
            int idx  = ph + i * 8;            // 0..95
            int k16l = idx >> 1;
            int half = idx & 1;
            uint4 val = *(const uint4*)&kcol[ol * KC_PAD + k16l * 16 + half * 8];
            ((uint4*)g_Wb)[((size_t)((kg * 48 + k16l) * 16 + nt)) * 64 + half * 32 + ol] = val;
        }
    }
}

// ---- fused basis + GEMM: 128 rows x 512 cols per block, K-split x4 ---------
__global__ __launch_bounds__(512, 2) void kan_gemm(const float* __restrict__ x,
                                                   float* __restrict__ out) {
    __shared__ __align__(16) ushort As[128 * APAD_ROW];   // 30720 B

    const int t    = threadIdx.x;
    const int lane = t & 63;
    const int w    = t >> 6;          // 0..7
    const int ln31 = lane & 31;
    const int half = lane >> 5;

    const int bx = blockIdx.x;
    const int mb = bx & 63;           // M-tile; bx%8 = mb%8 -> all 4 kp same XCD
    const int kp = bx >> 6;           // K-piece 0..3
    const int row_base = mb * 128;
    const int wn = w * 64;            // wave col base (wave tile 128 x 64)

    const int sm = t >> 2;            // staging row 0..127
    const int fh = t & 3;             // 2 feats per thread: fh*2, fh*2+1

    f32x16 acc[4][2] = {};            // 4 M-subtiles x 2 N-subtiles

    #pragma unroll 1
    for (int ii = 0; ii < ITERS; ++ii) {
        const int fbase = kp * 128 + ii * 8;
        // -- B prefetch: 12 frags, unique per wave, frag-linear coalesced
        uint4 breg[6][2];
        #pragma unroll
        for (int ks = 0; ks < 6; ++ks) {
            int k16g = kp * 96 + ii * 6 + ks;
            #pragma unroll
            for (int nt = 0; nt < 2; ++nt) {
                int ntg = w * 2 + nt;
                breg[ks][nt] = ((const uint4*)g_Wb)[((size_t)k16g * 16 + ntg) * 64 + lane];
            }
        }
        // -- x prefetch (2 feats/thread)
        const float2 xv = *(const float2*)&x[(size_t)(row_base + sm) * IN_F + fbase + fh * 2];

        __syncthreads();   // prev iteration's A-frag reads done before restaging

        // -- stage A tile: basis eval once per x element
        #pragma unroll
        for (int c = 0; c < 2; ++c) {
            float xx = c ? xv.y : xv.x;
            float wpos = (xx + 1.0f) * 7.0f;
            float fi = floorf(wpos);
            int   i  = (int)fi;
            float u  = wpos - fi;
            bool inr = (xx >= -1.0f) && (xx < 1.0f);
            int   q  = i - 3;
            float um = 1.0f - u;
            float uu = u * u, u3 = uu * u;
            const float C6 = 1.0f / 6.0f;
            float s0 = (inr && q >= 0) ? C6 : 0.0f;
            float s1 = (inr && q >= -1 && q <= 9) ? C6 : 0.0f;
            float s2 = (inr && q >= -2 && q <= 8) ? C6 : 0.0f;
            float s3 = (inr && q <= 7) ? C6 : 0.0f;
            uint b0 = f2bf(um * um * um * s0);
            uint b1 = f2bf((3.0f * u3 - 6.0f * uu + 4.0f) * s1);
            uint b2 = f2bf((-3.0f * u3 + 3.0f * uu + 3.0f * u + 1.0f) * s2);
            uint b3 = f2bf(u3 * s3);
            int r  = q & 1;
            int e0 = q & ~1;
            uint P0 = r ? (b0 << 16)        : (b0 | (b1 << 16));
            uint P1 = r ? (b1 | (b2 << 16)) : (b2 | (b3 << 16));
            uint P2 = r ? b3                : 0u;
            uint p[6];
            #pragma unroll
            for (int pi = 0; pi < 6; ++pi) {
                int d = 2 * pi - e0;
                p[pi] = (d == 0) ? P0 : (d == 2) ? P1 : (d == 4) ? P2 : 0u;
            }
            p[5] = (p[5] & 0xFFFFu) | ((uint)f2bf(xx) << 16);   // slot 11 = raw x
            ushort* rowp = &As[sm * APAD_ROW + (fh * 2 + c) * NSLOT];
            uint2 w0; w0.x = p[0]; w0.y = p[1];
            uint2 w1; w1.x = p[2]; w1.y = p[3];
            uint2 w2; w2.x = p[4]; w2.y = p[5];
            *(uint2*)&rowp[0] = w0;
            *(uint2*)&rowp[4] = w1;
            *(uint2*)&rowp[8] = w2;
        }

        __syncthreads();

        // -- MFMA: 6 k16-steps x 4 M-subtiles x 2 N-subtiles
        #pragma unroll
        for (int ks = 0; ks < 6; ++ks) {
            uint4 a[4];
            #pragma unroll
            for (int mt = 0; mt < 4; ++mt)
                a[mt] = *(const uint4*)&As[(mt * 32 + ln31) * APAD_ROW + ks * 16 + half * 8];
            #pragma unroll
            for (int mt = 0; mt < 4; ++mt) {
                bf16x8 af = __builtin_bit_cast(bf16x8, a[mt]);
                #pragma unroll
                for (int nt = 0; nt < 2; ++nt) {
                    bf16x8 bf = __builtin_bit_cast(bf16x8, breg[ks][nt]);
                    acc[mt][nt] = __builtin_amdgcn_mfma_f32_32x32x16_bf16(af, bf, acc[mt][nt], 0, 0, 0);
                }
            }
        }
    }

    // -- epilogue: C layout col=lane&31, row=(reg&3)+8*(reg>>2)+4*(lane>>5)
    #pragma unroll
    for (int mt = 0; mt < 4; ++mt) {
        #pragma unroll
        for (int nt = 0; nt < 2; ++nt) {
            int rb = row_base + mt * 32 + 4 * half;
            int cc = wn + nt * 32 + ln31;
            #pragma unroll
            for (int reg = 0; reg < 16; ++reg) {
                int rr = rb + (reg & 3) + 8 * (reg >> 2);
                unsafeAtomicAdd(&out[(size_t)rr * OUT_F + cc], acc[mt][nt][reg]);
            }
        }
    }
}

extern "C" void kernel_launch(void* const* d_in, const int* in_sizes, int n_in,
                              void* d_out, int out_size, void* d_ws, size_t ws_size,
                              hipStream_t stream) {
    const float* x  = (const float*)d_in[0];
    const float* bw = (const float*)d_in[1];
    const float* sw = (const float*)d_in[2];
    float* out = (float*)d_out;
    hipMemsetAsync(out, 0, (size_t)out_size * sizeof(float), stream);
    hipLaunchKernelGGL(prep_weights, dim3(128), dim3(256), 0, stream, bw, sw);
    hipLaunchKernelGGL(kan_gemm, dim3(64 * KSPLIT), dim3(512), 0, stream, x, out);
}